// Round 6
// baseline (401.886 us; speedup 1.0000x reference)
//
#include <hip/hip_runtime.h>

#define HW 16384

typedef __attribute__((ext_vector_type(8))) __bf16 bf16x8;
typedef __attribute__((ext_vector_type(16))) float floatx16;
typedef __attribute__((ext_vector_type(8))) unsigned short ushort8_t;

typedef const __attribute__((address_space(1))) unsigned int gu32;
typedef __attribute__((address_space(3))) unsigned int lu32;

__device__ __forceinline__ unsigned short f2bf(float f) {
    // round-to-nearest-even fp32 -> bf16
    unsigned int u = __builtin_bit_cast(unsigned int, f);
    unsigned int r = (u + 0x7FFFu + ((u >> 16) & 1u)) >> 16;
    return (unsigned short)r;
}

__device__ __forceinline__ void gload_lds16(const unsigned short* g, unsigned short* l) {
    __builtin_amdgcn_global_load_lds((gu32*)g, (lu32*)l, 16, 0, 0);
}

// Pre-convert W to bf16 in per-kt tiles [256 rows][64 k], XOR-swizzled so the main
// kernel can global_load_lds linearly and ds_read with the same involution.
// ushort index within tile: (row*64 + kl) ^ ((row&7)<<3); tile kt base = kt*16384.
__global__ void wconv_kernel(const float* __restrict__ w, unsigned short* __restrict__ wb) {
    int i = blockIdx.x * 256 + threadIdx.x;   // 65536 elements, i = row*256 + c
    int row = i >> 8, c = i & 255;
    int kt = c >> 6, kl = c & 63;
    int idx = (row * 64 + kl) ^ ((row & 7) << 3);
    wb[kt * 16384 + idx] = f2bf(w[i]);
}

// Block: 256 out-ch x 128 px, K=256. 8 waves: pw = wv>>1 (32-px window),
// sub = wv&1 (q-half). Wave computes mt = {sub, 2+sub, 4+sub, 6+sub} 32-row tiles
// (mfma_32x32x16, acc = 4 x f32x16 = 64 VGPR) so the 4 lifting partners
// (q, q+64, q+128, q+192) are acc[0..3] at the same reg -> lane-local epilogue.
// W: 2x32KB LDS dbuf via pre-swizzled global_load_lds; per-kt sync is raw s_barrier
// + counted vmcnt(16) (waits only W; in-flight X loads cross the barrier).
// X: direct-to-reg, half-kt (32-ch) prefetch double-buffer xf0/xf1.
// 2 blocks/CU (64KB LDS, ~110 VGPR) -> one block's write burst overlaps the other's reads.
__global__ __launch_bounds__(512, 4) void fused_gemm_lift(
        const float* __restrict__ x,
        const unsigned short* __restrict__ wb,
        const float* __restrict__ lp_v,
        const float* __restrict__ hp_v,
        const float* __restrict__ lp_h,
        const float* __restrict__ hp_h,
        float* __restrict__ out) {
    __shared__ alignas(16) unsigned short wbuf_s[2][16384];  // 2 x 32 KB W kt-tiles

    const int tid  = threadIdx.x;
    const int wv   = tid >> 6;
    const int lane = tid & 63;
    const int pw   = wv >> 1;       // 32-px window
    const int sub  = wv & 1;        // q-half
    const int tile = blockIdx.x & 127;
    const int bb   = blockIdx.x >> 7;
    const int p0   = tile * 128;

    const int l31 = lane & 31;      // pixel within window / row within m-tile
    const int hi  = lane >> 5;      // 8-ch k-chunk select

    const float* xp = x + (size_t)bb * 256 * HW + p0 + pw * 32 + l31;

    floatx16 acc[4];
    #pragma unroll
    for (int j4 = 0; j4 < 4; ++j4)
        #pragma unroll
        for (int e = 0; e < 16; ++e) acc[j4][e] = 0.f;

    float xf0[16], xf1[16];

    // ---- prologue: W[0] -> wbuf[0] (4 gloads), X half0 -> xf0 (16 loads) ----
    #pragma unroll
    for (int p = 0; p < 4; ++p)
        gload_lds16(wb + (size_t)(p * 512 + tid) * 8, &wbuf_s[0][(p * 512 + tid) * 8]);
    #pragma unroll
    for (int k16 = 0; k16 < 2; ++k16)
        #pragma unroll
        for (int j = 0; j < 8; ++j)
            xf0[k16 * 8 + j] = xp[(size_t)(k16 * 16 + hi * 8 + j) * HW];
    asm volatile("s_waitcnt vmcnt(16)" ::: "memory");   // W done; X still in flight
    __builtin_amdgcn_sched_barrier(0);
    __builtin_amdgcn_s_barrier();
    __builtin_amdgcn_sched_barrier(0);

    #pragma unroll
    for (int kt = 0; kt < 4; ++kt) {
        const int cw = kt & 1;

        // issue W[kt+1] (oldest VMEM of this iteration)
        if (kt < 3) {
            #pragma unroll
            for (int p = 0; p < 4; ++p)
                gload_lds16(wb + (size_t)(kt + 1) * 16384 + (size_t)(p * 512 + tid) * 8,
                            &wbuf_s[cw ^ 1][(p * 512 + tid) * 8]);
        }

        // issue X half (2kt+1) -> xf1
        {
            const int cb = kt * 64 + 32;
            #pragma unroll
            for (int k16 = 0; k16 < 2; ++k16)
                #pragma unroll
                for (int j = 0; j < 8; ++j)
                    xf1[k16 * 8 + j] = xp[(size_t)(cb + k16 * 16 + hi * 8 + j) * HW];
        }

        // compute half A (k-local 0..31) from xf0
        #pragma unroll
        for (int k16 = 0; k16 < 2; ++k16) {
            ushort8_t u;
            #pragma unroll
            for (int j = 0; j < 8; ++j) u[j] = f2bf(xf0[k16 * 8 + j]);
            const bf16x8 bq = __builtin_bit_cast(bf16x8, u);
            const int kl = k16 * 16 + hi * 8;
            #pragma unroll
            for (int j4 = 0; j4 < 4; ++j4) {
                const int row = (2 * j4 + sub) * 32 + l31;
                bf16x8 af = *reinterpret_cast<const bf16x8*>(
                    &wbuf_s[cw][(row * 64 + kl) ^ ((row & 7) << 3)]);
                acc[j4] = __builtin_amdgcn_mfma_f32_32x32x16_bf16(af, bq, acc[j4], 0, 0, 0);
            }
        }

        // issue X half (2kt+2) -> xf0
        if (kt < 3) {
            const int cb = kt * 64 + 64;
            #pragma unroll
            for (int k16 = 0; k16 < 2; ++k16)
                #pragma unroll
                for (int j = 0; j < 8; ++j)
                    xf0[k16 * 8 + j] = xp[(size_t)(cb + k16 * 16 + hi * 8 + j) * HW];
        }

        // compute half B (k-local 32..63) from xf1
        #pragma unroll
        for (int k16 = 0; k16 < 2; ++k16) {
            ushort8_t u;
            #pragma unroll
            for (int j = 0; j < 8; ++j) u[j] = f2bf(xf1[k16 * 8 + j]);
            const bf16x8 bq = __builtin_bit_cast(bf16x8, u);
            const int kl = 32 + k16 * 16 + hi * 8;
            #pragma unroll
            for (int j4 = 0; j4 < 4; ++j4) {
                const int row = (2 * j4 + sub) * 32 + l31;
                bf16x8 af = *reinterpret_cast<const bf16x8*>(
                    &wbuf_s[cw][(row * 64 + kl) ^ ((row & 7) << 3)]);
                acc[j4] = __builtin_amdgcn_mfma_f32_32x32x16_bf16(af, bq, acc[j4], 0, 0, 0);
            }
        }

        // raw barrier: wait only W[kt+1] (vmcnt(16) leaves the 16 X loads in flight)
        if (kt < 3) {
            asm volatile("s_waitcnt vmcnt(16)" ::: "memory");
            __builtin_amdgcn_sched_barrier(0);
            __builtin_amdgcn_s_barrier();
            __builtin_amdgcn_sched_barrier(0);
        }
    }

    // ---- fused lifting epilogue (lane-local) ----
    // 32x32 C/D map: col = lane&31, rowlocal = (reg&3) + 8*(reg>>2) + 4*(lane>>5)
    const int px = p0 + pw * 32 + l31;
    const int h  = px >> 7;
    const int w  = px & 127;
    float* outbase = out + (size_t)bb * 64 * 65536 + (size_t)(2 * h) * 256 + 2 * w;
    #pragma unroll
    for (int reg = 0; reg < 16; ++reg) {
        const int rowl = (reg & 3) + 8 * (reg >> 2) + 4 * hi;
        const int q = sub * 32 + rowl;
        const float2 lv = *reinterpret_cast<const float2*>(lp_v + 2 * q);
        const float2 hv = *reinterpret_cast<const float2*>(hp_v + 2 * q);
        const float2 lh = *reinterpret_cast<const float2*>(lp_h + 2 * q);
        const float2 hh = *reinterpret_cast<const float2*>(hp_h + 2 * q);
        const float a  = acc[0][reg];
        const float b2 = acc[1][reg];
        const float c2 = acc[2][reg];
        const float d2 = acc[3][reg];
        const float xl0 = lv.x * a + lv.y * b2;   // x_l even output row
        const float xl1 = hv.x * a + hv.y * b2;   // x_l odd output row
        const float xh0 = lv.x * c2 + lv.y * d2;  // x_h even
        const float xh1 = hv.x * c2 + hv.y * d2;  // x_h odd
        float2 r0 = make_float2(lh.x * xl0 + lh.y * xh0, hh.x * xl0 + hh.y * xh0);
        float2 r1 = make_float2(lh.x * xl1 + lh.y * xh1, hh.x * xl1 + hh.y * xh1);
        float* oq = outbase + (size_t)q * 65536;
        *reinterpret_cast<float2*>(oq)       = r0;
        *reinterpret_cast<float2*>(oq + 256) = r1;
    }
}

extern "C" void kernel_launch(void* const* d_in, const int* in_sizes, int n_in,
                              void* d_out, int out_size, void* d_ws, size_t ws_size,
                              hipStream_t stream) {
    const float* x   = (const float*)d_in[0];
    const float* w   = (const float*)d_in[1];
    const float* lpv = (const float*)d_in[2];
    const float* hpv = (const float*)d_in[3];
    const float* lph = (const float*)d_in[4];
    const float* hph = (const float*)d_in[5];
    float* outp = (float*)d_out;
    unsigned short* wbp = (unsigned short*)d_ws;   // 128 KB bf16 weights, pre-swizzled tiles

    wconv_kernel<<<dim3(256), dim3(256), 0, stream>>>(w, wbp);
    fused_gemm_lift<<<dim3(2048), dim3(512), 0, stream>>>(x, wbp, lpv, hpv, lph, hph, outp);
}

// Round 7
// 137.880 us; speedup vs baseline: 2.9147x; 2.9147x over previous
//
#include <hip/hip_runtime.h>

#define HW 16384

typedef __attribute__((ext_vector_type(8))) __bf16 bf16x8;
typedef __attribute__((ext_vector_type(16))) float floatx16;
typedef __attribute__((ext_vector_type(8))) unsigned short ushort8_t;

typedef const __attribute__((address_space(1))) unsigned int gu32;
typedef __attribute__((address_space(3))) unsigned int lu32;

__device__ __forceinline__ unsigned short f2bf(float f) {
    // round-to-nearest-even fp32 -> bf16
    unsigned int u = __builtin_bit_cast(unsigned int, f);
    unsigned int r = (u + 0x7FFFu + ((u >> 16) & 1u)) >> 16;
    return (unsigned short)r;
}

__device__ __forceinline__ void gload_lds16(const void* g, void* l) {
    __builtin_amdgcn_global_load_lds((gu32*)g, (lu32*)l, 16, 0, 0);
}

// Pre-convert W to bf16 in per-kt tiles [256 rows][64 k], XOR-swizzled so the main
// kernel can global_load_lds linearly and ds_read with the same involution.
// ushort index within tile: (row*64 + kl) ^ ((row&7)<<3); tile kt base = kt*16384.
__global__ void wconv_kernel(const float* __restrict__ w, unsigned short* __restrict__ wb) {
    int i = blockIdx.x * 256 + threadIdx.x;   // 65536 elements, i = row*256 + c
    int row = i >> 8, c = i & 255;
    int kt = c >> 6, kl = c & 63;
    int idx = (row * 64 + kl) ^ ((row & 7) << 3);
    wb[kt * 16384 + idx] = f2bf(w[i]);
}

// Block: 256 out-ch x 128 px (one conv row), K=256 in 4 kt-steps.
// 8 waves: pw = wv>>1 (32-px window), sub = wv&1 (q-half). Wave's m-tiles
// mt = {sub, 2+sub, 4+sub, 6+sub} (mfma_32x32x16, acc = 4 x f32x16) so lifting
// partners (q, q+64, q+128, q+192) = acc[0..3] at the same reg -> lane-local.
// X: LDS dbuf of RAW fp32 tiles [64 c][128 px] via global_load_lds (1KB/wave-instr
// contiguous reads); fragment build = 8 conflict-free ds_read_b32 + f2bf pack.
// W: LDS dbuf, pre-swizzled, issued pre-compute. Counted vmcnt(4) keeps next X
// tile in flight across barriers. Epilogue: deposit lifted outputs to LDS, then
// cooperative float4 stores writing FULL 1KB output rows per wave-instr.
__global__ __launch_bounds__(512, 2) void fused_gemm_lift(
        const float* __restrict__ x,
        const unsigned short* __restrict__ wb,
        const float* __restrict__ lp_v,
        const float* __restrict__ hp_v,
        const float* __restrict__ lp_h,
        const float* __restrict__ hp_h,
        float* __restrict__ out) {
    __shared__ alignas(16) unsigned char smem[131072];  // xb0|xb1|wbb0|wbb1 (4 x 32 KB)

    float* xb0 = (float*)smem;
    float* xb1 = (float*)(smem + 32768);
    unsigned short* wbb0 = (unsigned short*)(smem + 65536);
    unsigned short* wbb1 = (unsigned short*)(smem + 98304);

    const int tid  = threadIdx.x;
    const int wv   = tid >> 6;
    const int lane = tid & 63;
    const int pw   = wv >> 1;       // 32-px window
    const int sub  = wv & 1;        // q-half
    const int t    = blockIdx.x & 127;   // conv row
    const int bb   = blockIdx.x >> 7;    // batch
    const int p0   = t * 128;

    const int l31 = lane & 31;
    const int hi  = lane >> 5;
    const int px  = pw * 32 + l31;  // pixel within the 128-px row

    const float* xg = x + (size_t)bb * 256 * HW + p0;

    floatx16 acc[4];
    #pragma unroll
    for (int j4 = 0; j4 < 4; ++j4)
        #pragma unroll
        for (int e = 0; e < 16; ++e) acc[j4][e] = 0.f;

    // ---- staging macros (4 gload_lds each; 1 KB contiguous per wave-instr) ----
    #define STAGE_X(KT, BUF) do {                                              \
        _Pragma("unroll")                                                      \
        for (int i_ = 0; i_ < 4; ++i_) {                                       \
            int g_ = i_ * 512 + tid;                                           \
            int c_ = (KT) * 64 + (g_ >> 5);                                    \
            int o_ = (g_ & 31) * 4;                                            \
            gload_lds16(xg + (size_t)c_ * HW + o_, (char*)(BUF) + g_ * 16);    \
        } } while (0)

    #define STAGE_W(KT, BUF) do {                                              \
        _Pragma("unroll")                                                      \
        for (int p_ = 0; p_ < 4; ++p_) {                                       \
            int idx_ = p_ * 512 + tid;                                         \
            gload_lds16(wb + (size_t)(KT) * 16384 + (size_t)idx_ * 8,          \
                        (char*)(BUF) + idx_ * 16);                             \
        } } while (0)

    #define COMPUTE(XBF, WBF) do {                                             \
        _Pragma("unroll")                                                      \
        for (int k16_ = 0; k16_ < 4; ++k16_) {                                 \
            const int kl_ = k16_ * 16 + hi * 8;                                \
            float xv_[8];                                                      \
            _Pragma("unroll")                                                  \
            for (int j_ = 0; j_ < 8; ++j_)                                     \
                xv_[j_] = (XBF)[(kl_ + j_) * 128 + px];                        \
            ushort8_t u_;                                                      \
            _Pragma("unroll")                                                  \
            for (int j_ = 0; j_ < 8; ++j_) u_[j_] = f2bf(xv_[j_]);             \
            const bf16x8 bq_ = __builtin_bit_cast(bf16x8, u_);                 \
            _Pragma("unroll")                                                  \
            for (int j4_ = 0; j4_ < 4; ++j4_) {                                \
                const int row_ = (2 * j4_ + sub) * 32 + l31;                   \
                bf16x8 af_ = *reinterpret_cast<const bf16x8*>(                 \
                    &(WBF)[(row_ * 64 + kl_) ^ ((row_ & 7) << 3)]);            \
                acc[j4_] = __builtin_amdgcn_mfma_f32_32x32x16_bf16(            \
                    af_, bq_, acc[j4_], 0, 0, 0);                              \
            }                                                                  \
        } } while (0)

    // ---- prologue: X0 -> xb0, W0 -> wbb0, X1 -> xb1 ----
    STAGE_X(0, xb0);
    STAGE_W(0, wbb0);
    STAGE_X(1, xb1);
    asm volatile("s_waitcnt vmcnt(4)" ::: "memory");  // X0+W0 landed; X1 in flight
    __builtin_amdgcn_s_barrier();

    // kt = 0
    STAGE_W(1, wbb1);
    COMPUTE(xb0, wbb0);
    __builtin_amdgcn_s_barrier();                     // done reading xb0/wbb0
    STAGE_X(2, xb0);
    asm volatile("s_waitcnt vmcnt(4)" ::: "memory");  // X1+W1 landed; X2 in flight
    __builtin_amdgcn_s_barrier();

    // kt = 1
    STAGE_W(2, wbb0);
    COMPUTE(xb1, wbb1);
    __builtin_amdgcn_s_barrier();
    STAGE_X(3, xb1);
    asm volatile("s_waitcnt vmcnt(4)" ::: "memory");  // X2+W2 landed; X3 in flight
    __builtin_amdgcn_s_barrier();

    // kt = 2
    STAGE_W(3, wbb1);
    COMPUTE(xb0, wbb0);
    __builtin_amdgcn_s_barrier();
    asm volatile("s_waitcnt vmcnt(0)" ::: "memory");  // X3+W3 landed
    __builtin_amdgcn_s_barrier();

    // kt = 3
    COMPUTE(xb1, wbb1);
    __syncthreads();   // all reads done before LDS reuse by epilogue

    // ---- epilogue: lift in regs -> LDS chunk -> full-row float4 stores ----
    // 32x32 C/D map: col = lane&31 (pixel), rowl = (reg&3) + 8*(reg>>2) + 4*(lane>>5)
    float* chunk = (float*)smem;   // 64 KB: [32 q][2 r][256 w]
    #pragma unroll
    for (int qc = 0; qc < 2; ++qc) {
        if (sub == qc) {
            #pragma unroll
            for (int reg = 0; reg < 16; ++reg) {
                const int rowl = (reg & 3) + 8 * (reg >> 2) + 4 * hi;
                const int q = sub * 32 + rowl;
                const float2 lv = *reinterpret_cast<const float2*>(lp_v + 2 * q);
                const float2 hv = *reinterpret_cast<const float2*>(hp_v + 2 * q);
                const float2 lh = *reinterpret_cast<const float2*>(lp_h + 2 * q);
                const float2 hh = *reinterpret_cast<const float2*>(hp_h + 2 * q);
                const float a  = acc[0][reg];
                const float b2 = acc[1][reg];
                const float c2 = acc[2][reg];
                const float d2 = acc[3][reg];
                const float xl0 = lv.x * a + lv.y * b2;   // even output row
                const float xl1 = hv.x * a + hv.y * b2;   // odd output row
                const float xh0 = lv.x * c2 + lv.y * d2;
                const float xh1 = hv.x * c2 + hv.y * d2;
                float2 r0 = make_float2(lh.x * xl0 + lh.y * xh0, hh.x * xl0 + hh.y * xh0);
                float2 r1 = make_float2(lh.x * xl1 + lh.y * xh1, hh.x * xl1 + hh.y * xh1);
                *reinterpret_cast<float2*>(&chunk[(rowl * 2 + 0) * 256 + 2 * px]) = r0;
                *reinterpret_cast<float2*>(&chunk[(rowl * 2 + 1) * 256 + 2 * px]) = r1;
            }
        }
        __syncthreads();
        // cooperative store: each wave-instr writes one full 1 KB output row
        #pragma unroll
        for (int i = 0; i < 8; ++i) {
            const int g = i * 512 + tid;          // float4 index in chunk
            const int rowid = g >> 6;             // [0,64): qloc*2 + r
            const int qloc  = rowid >> 1;
            const int r     = rowid & 1;
            const int col   = (g & 63) * 4;
            float4 v = reinterpret_cast<const float4*>(chunk)[g];
            *reinterpret_cast<float4*>(
                out + (size_t)(bb * 64 + qc * 32 + qloc) * 65536
                    + (size_t)(2 * t + r) * 256 + col) = v;
        }
        __syncthreads();
    }

    #undef STAGE_X
    #undef STAGE_W
    #undef COMPUTE
}

extern "C" void kernel_launch(void* const* d_in, const int* in_sizes, int n_in,
                              void* d_out, int out_size, void* d_ws, size_t ws_size,
                              hipStream_t stream) {
    const float* x   = (const float*)d_in[0];
    const float* w   = (const float*)d_in[1];
    const float* lpv = (const float*)d_in[2];
    const float* hpv = (const float*)d_in[3];
    const float* lph = (const float*)d_in[4];
    const float* hph = (const float*)d_in[5];
    float* outp = (float*)d_out;
    unsigned short* wbp = (unsigned short*)d_ws;   // 128 KB bf16 weights, pre-swizzled tiles

    wconv_kernel<<<dim3(256), dim3(256), 0, stream>>>(w, wbp);
    fused_gemm_lift<<<dim3(2048), dim3(512), 0, stream>>>(x, wbp, lpv, hpv, lph, hph, outp);
}